// Round 1
// baseline (15137.442 us; speedup 1.0000x reference)
//
#include <hip/hip_runtime.h>
#include <hip/hip_cooperative_groups.h>
#include <cstdio>

namespace cg = cooperative_groups;

typedef __bf16 bf16x8 __attribute__((ext_vector_type(8)));
typedef float f32x4 __attribute__((ext_vector_type(4)));

#define DEV __device__ __forceinline__

DEV short f2bf(float f) {
    unsigned u = __builtin_bit_cast(unsigned, f);
    u += 0x7fffu + ((u >> 16) & 1u);   // RNE
    return (short)(u >> 16);
}
DEV float bf2f(short s) {
    unsigned u = ((unsigned)(unsigned short)s) << 16;
    return __builtin_bit_cast(float, u);
}
DEV float sigmoidf_(float x) { return 1.0f / (1.0f + __expf(-x)); }
DEV float tanhf_(float x) { float e = __expf(2.0f * x); return 1.0f - 2.0f / (e + 1.0f); }

DEV void gload_lds16(const void* g, void* l) {
    __builtin_amdgcn_global_load_lds(
        (__attribute__((address_space(1))) void*)(g),
        (__attribute__((address_space(3))) void*)(l), 16, 0, 0);
}

DEV f32x4 mfma16(bf16x8 a, bf16x8 b, f32x4 c) {
    return __builtin_amdgcn_mfma_f32_16x16x32_bf16(a, b, c, 0, 0, 0);
}

// ---------------- f32 -> bf16 convert ----------------
__global__ void f2bf_vec(const float* __restrict__ in, short* __restrict__ out, int n4) {
    int i = blockIdx.x * 256 + threadIdx.x;
    if (i >= n4) return;
    float4 v = reinterpret_cast<const float4*>(in)[i];
    short4 o;
    o.x = f2bf(v.x); o.y = f2bf(v.y); o.z = f2bf(v.z); o.w = f2bf(v.w);
    reinterpret_cast<short4*>(out)[i] = o;
}

// ---------------- GEMM: C[m,n] = sum_k A[m,k] * W[n,k] + bias[n] ----------------
// A rows are mode-dependent gathers. 128x128 tile, BK=64, 4 waves (2x2 of 64x64).
enum { M_XW1 = 0, M_UAW = 1, M_UAS = 2, M_XW2 = 3 };

template<int MODE>
__global__ __launch_bounds__(256) void gemm_bt(
    const short* __restrict__ Abase, const short* __restrict__ A2,
    const int* __restrict__ tok0, const int* __restrict__ tok1,
    const short* __restrict__ W, const float* __restrict__ bias,
    short* __restrict__ C, int M, int N, int K)
{
    __shared__ short Als[128 * 64];
    __shared__ short Bls[128 * 64];
    int tid = threadIdx.x;
    int m0 = blockIdx.y * 128, n0 = blockIdx.x * 128;
    int kc = (tid & 7) * 8;

    // Precompute A row base pointers for the 4 staging rounds (row = i*32 + tid/8)
    const short* arow[4];
#pragma unroll
    for (int i = 0; i < 4; i++) {
        int gm = m0 + i * 32 + (tid >> 3);
        if (MODE == M_XW1) {
            int t = gm >> 8, s = gm & 255;
            int tok = (s < 128) ? tok0[s * 256 + t] : tok1[(s - 128) * 256 + t];
            arow[i] = Abase + (size_t)tok * 512;
        } else if (MODE == M_UAW) {
            int t = gm >> 7, b = gm & 127;
            arow[i] = Abase + (size_t)tok0[b * 256 + t] * 512;
        } else if (MODE == M_UAS) {
            int t = gm >> 7, b = gm & 127;
            arow[i] = Abase + ((size_t)t * 256 + b) * 512;
        } else {
            arow[i] = Abase + (size_t)gm * 512;   // ctx_word part (k<512)
        }
    }

    f32x4 acc[4][4] = {};
    int l = tid & 63, w = tid >> 6;
    int wm = (w >> 1) * 64, wn = (w & 1) * 64;

    for (int kt = 0; kt < K; kt += 64) {
#pragma unroll
        for (int i = 0; i < 4; i++) {
            const short* asrc;
            if (MODE == M_XW2) {
                int gm = m0 + i * 32 + (tid >> 3);
                const short* base = (kt < 512) ? Abase : A2;
                asrc = base + (size_t)gm * 512 + (kt & 511) + kc;
            } else {
                asrc = arow[i] + kt + kc;
            }
            gload_lds16(asrc, &Als[i * 2048 + tid * 8]);
        }
#pragma unroll
        for (int i = 0; i < 4; i++) {
            const short* bsrc = W + (size_t)(n0 + i * 32 + (tid >> 3)) * K + kt + kc;
            gload_lds16(bsrc, &Bls[i * 2048 + tid * 8]);
        }
        __syncthreads();
#pragma unroll
        for (int kk = 0; kk < 2; kk++) {
            int ko = kk * 32 + (l >> 4) * 8;
            bf16x8 af[4], bfr[4];
#pragma unroll
            for (int mi = 0; mi < 4; mi++)
                af[mi] = *(const bf16x8*)&Als[(wm + mi * 16 + (l & 15)) * 64 + ko];
#pragma unroll
            for (int ni = 0; ni < 4; ni++)
                bfr[ni] = *(const bf16x8*)&Bls[(wn + ni * 16 + (l & 15)) * 64 + ko];
#pragma unroll
            for (int mi = 0; mi < 4; mi++)
#pragma unroll
                for (int ni = 0; ni < 4; ni++)
                    acc[mi][ni] = mfma16(af[mi], bfr[ni], acc[mi][ni]);
        }
        __syncthreads();
    }
    // epilogue: + bias, store bf16. C/D layout: col = l&15, row = (l>>4)*4 + j
#pragma unroll
    for (int ni = 0; ni < 4; ni++) {
        int col = n0 + wn + ni * 16 + (l & 15);
        float bv = bias[col];
#pragma unroll
        for (int mi = 0; mi < 4; mi++) {
            int row0 = m0 + wm + mi * 16 + (l >> 4) * 4;
#pragma unroll
            for (int j = 0; j < 4; j++)
                C[(size_t)(row0 + j) * N + col] = f2bf(acc[mi][ni][j] + bv);
        }
    }
}

// ---------------- GRU scan (cooperative) ----------------
// grid = (32 col-blocks of 16 h-cols, S/32 row-blocks), 64 threads (1 wave).
// Wh slice (48 gate-rows x 512) lives in LDS (XOR-swizzled) for all steps.
// h double-buffered bf16 in global; own h slice kept in registers for z*h.
template<int WRITE_ALL, int COOP>
__global__ __launch_bounds__(64) void gru_scan(
    const short* __restrict__ xW,   // [T][S][1536] bf16 (includes bi)
    const short* __restrict__ Whb,  // [1536][512] bf16
    const float* __restrict__ bh,   // [1536]
    short* __restrict__ hb0, short* __restrict__ hb1,  // [S][512] bf16
    short* __restrict__ h_all,      // [T][S][512] bf16 (WRITE_ALL)
    float* __restrict__ h_final,    // [S][512] f32 (!WRITE_ALL, t==T-1)
    int S, int t0, int tend, int T)
{
    __shared__ short Wl[48 * 512];  // 49152 B
    int cb = blockIdx.x, rb = blockIdx.y;
    int l = threadIdx.x;
    int r0 = rb * 32, cw = cb * 16;
    int lrow = l & 15, lk = (l >> 4) * 8;

    // stage Wh slice: local row g in [0,48) -> phys gate row (g/16)*512 + cw + (g%16)
    for (int i = l; i < 48 * 512 / 8; i += 64) {
        int byte = i * 16;
        int g = byte >> 10;
        int kb = byte & 1023;
        int phys = (g >> 4) * 512 + cw + (g & 15);
        int dst = (g << 10) | (kb ^ ((g & 7) << 4));
        *(int4*)((char*)Wl + dst) = *(const int4*)((const char*)Whb + (size_t)phys * 1024 + kb);
    }
    __syncthreads();

    float bhv[3];
#pragma unroll
    for (int g = 0; g < 3; g++) bhv[g] = bh[g * 512 + cw + lrow];

    float hreg[2][4] = {};
    const short* cur = hb0;
    short* nxt = hb1;

    for (int t = t0; t < tend; t++) {
        f32x4 acc[2][3] = {};
        if (t > 0) {
#pragma unroll 4
            for (int kk = 0; kk < 16; kk++) {
                int kofs = kk * 32 + lk;
                bf16x8 a0 = *(const bf16x8*)(cur + (size_t)(r0 + lrow) * 512 + kofs);
                bf16x8 a1 = *(const bf16x8*)(cur + (size_t)(r0 + 16 + lrow) * 512 + kofs);
#pragma unroll
                for (int g = 0; g < 3; g++) {
                    int row = g * 16 + lrow;
                    int boff = (row << 10) + ((kofs * 2) ^ ((row & 7) << 4));
                    bf16x8 bfr = *(const bf16x8*)((const char*)Wl + boff);
                    acc[0][g] = mfma16(a0, bfr, acc[0][g]);
                    acc[1][g] = mfma16(a1, bfr, acc[1][g]);
                }
            }
        }
#pragma unroll
        for (int mi = 0; mi < 2; mi++) {
#pragma unroll
            for (int j = 0; j < 4; j++) {
                int srow = r0 + mi * 16 + (l >> 4) * 4 + j;
                const short* xp = xW + ((size_t)t * S + srow) * 1536 + cw + lrow;
                float xr = bf2f(xp[0]);
                float xz = bf2f(xp[512]);
                float xn = bf2f(xp[1024]);
                float r = sigmoidf_(xr + acc[mi][0][j] + bhv[0]);
                float z = sigmoidf_(xz + acc[mi][1][j] + bhv[1]);
                float n = tanhf_(xn + r * (acc[mi][2][j] + bhv[2]));
                float h = (1.f - z) * n + z * hreg[mi][j];
                hreg[mi][j] = h;
                size_t off = (size_t)srow * 512 + cw + lrow;
                short hb16 = f2bf(h);
                nxt[off] = hb16;
                if (WRITE_ALL) h_all[(size_t)t * S * 512 + off] = hb16;
                else if (t == T - 1) h_final[off] = h;
            }
        }
        if (COOP && (t + 1 < tend)) cg::this_grid().sync();
        const short* tmp = cur; cur = nxt; nxt = (short*)tmp;
    }
}

// ---------------- per-(b) sums: u_all_sum ----------------
__global__ void embed_sum_k(const short* __restrict__ ebf, const int* __restrict__ tok,
                            float* __restrict__ out) {
    int b = blockIdx.x, d = threadIdx.x;
    float a0 = 0.f, a1 = 0.f;
    for (int t = 0; t < 256; t++) {
        const short* row = ebf + (size_t)tok[b * 256 + t] * 512;
        a0 += bf2f(row[d]); a1 += bf2f(row[d + 256]);
    }
    out[b * 512 + d] = a0; out[b * 512 + d + 256] = a1;
}
__global__ void hall_sum_k(const short* __restrict__ h_all, float* __restrict__ out) {
    int b = blockIdx.x, d = threadIdx.x;
    float a0 = 0.f, a1 = 0.f;
    for (int t = 0; t < 256; t++) {
        const short* row = h_all + ((size_t)t * 256 + b) * 512;
        a0 += bf2f(row[d]); a1 += bf2f(row[d + 256]);
    }
    out[b * 512 + d] = a0; out[b * 512 + d + 256] = a1;
}

// ---------------- dual attention combine (one wave per (t,b)) ----------------
template<int WORD>
__global__ __launch_bounds__(256) void attn_combine(
    const short* __restrict__ uA, const short* __restrict__ rsrc,
    const int* __restrict__ rtok, const float* __restrict__ usum,
    const float* __restrict__ Wv, short* __restrict__ ctx)
{
    int l = threadIdx.x & 63, w = threadIdx.x >> 6;
    int m = blockIdx.x * 4 + w;
    int t = m >> 7, b = m & 127;
    const short* rrow;
    if (WORD) rrow = rsrc + (size_t)rtok[b * 256 + t] * 512;
    else      rrow = rsrc + ((size_t)t * 256 + 128 + b) * 512;
    const short* urow = uA + (size_t)m * 512;
    int d0 = l * 8;
    short ru[8], uu[8];
    *(int4*)ru = *(const int4*)(rrow + d0);
    *(int4*)uu = *(const int4*)(urow + d0);
    float rv[8], dot = 0.f;
#pragma unroll
    for (int i = 0; i < 8; i++) { rv[i] = bf2f(ru[i]); dot += rv[i] * bf2f(uu[i]); }
#pragma unroll
    for (int off = 32; off >= 1; off >>= 1) dot += __shfl_xor(dot, off);
    float tw = tanhf_(dot);
    float e[8], se = 0.f;
#pragma unroll
    for (int i = 0; i < 8; i++) { e[i] = __expf(tw * Wv[d0 + i]); se += e[i]; }
#pragma unroll
    for (int off = 32; off >= 1; off >>= 1) se += __shfl_xor(se, off);
    float inv = 1.f / se;
    short ov[8];
#pragma unroll
    for (int i = 0; i < 8; i++) ov[i] = f2bf(e[i] * inv * usum[b * 512 + d0 + i] * rv[i]);
    *(int4*)(ctx + (size_t)m * 512 + d0) = *(int4*)ov;
}

// ---------------- final classifier + softmax ----------------
__global__ void final_head_k(const float* __restrict__ h2, const float* __restrict__ Wf,
                             const float* __restrict__ bfv, float* __restrict__ out) {
    int b = blockIdx.x, l = threadIdx.x;  // 64 threads
    float d0 = 0.f, d1 = 0.f;
    for (int k = l; k < 512; k += 64) {
        float h = h2[b * 512 + k];
        d0 += h * Wf[k];
        d1 += h * Wf[512 + k];
    }
#pragma unroll
    for (int off = 32; off >= 1; off >>= 1) { d0 += __shfl_xor(d0, off); d1 += __shfl_xor(d1, off); }
    if (l == 0) {
        float l0 = d0 + bfv[0], l1 = d1 + bfv[1];
        float mx = fmaxf(l0, l1);
        float e0 = __expf(l0 - mx), e1 = __expf(l1 - mx);
        float s = e0 + e1;
        out[b * 2] = e0 / s; out[b * 2 + 1] = e1 / s;
    }
}

extern "C" void kernel_launch(void* const* d_in, const int* in_sizes, int n_in,
                              void* d_out, int out_size, void* d_ws, size_t ws_size,
                              hipStream_t stream)
{
    const int* ask    = (const int*)d_in[0];
    const int* answer = (const int*)d_in[1];
    const int* askkw  = (const int*)d_in[2];
    const int* anskw  = (const int*)d_in[3];
    const float* embed = (const float*)d_in[4];
    const float* Wi1 = (const float*)d_in[5];
    const float* Wh1 = (const float*)d_in[6];
    const float* bi1 = (const float*)d_in[7];
    const float* bh1 = (const float*)d_in[8];
    const float* Aw  = (const float*)d_in[9];
    const float* bw  = (const float*)d_in[10];
    const float* Ww  = (const float*)d_in[11];
    const float* As  = (const float*)d_in[12];
    const float* bs  = (const float*)d_in[13];
    const float* Ws  = (const float*)d_in[14];
    const float* Wi2 = (const float*)d_in[15];
    const float* Wh2 = (const float*)d_in[16];
    const float* bi2 = (const float*)d_in[17];
    const float* bh2 = (const float*)d_in[18];
    const float* Wf  = (const float*)d_in[19];
    const float* bfv = (const float*)d_in[20];

    char* ws = (char*)d_ws;
    size_t off = 0;
    auto alloc = [&](size_t bytes) -> void* {
        void* p = (void*)(ws + off);
        off += (bytes + 255) & ~(size_t)255;
        return p;
    };
    short* embed_bf = (short*)alloc(50000ULL * 512 * 2);
    short* Wi1b = (short*)alloc(1536 * 512 * 2);
    short* Wh1b = (short*)alloc(1536 * 512 * 2);
    short* Awb  = (short*)alloc(512 * 512 * 2);
    short* Asb  = (short*)alloc(512 * 512 * 2);
    short* Wi2b = (short*)alloc(1536 * 1024 * 2);
    short* Wh2b = (short*)alloc(1536 * 512 * 2);
    char* X = (char*)alloc(201326592ULL);            // xW1 region, reused after GRU1
    short* xW1  = (short*)X;                         // [256][256][1536] bf16
    short* uA   = (short*)X;                         // [32768][512] bf16 (after GRU1)
    short* ctxW = (short*)(X + 33554432);            // [256][128][512] bf16
    short* ctxS = (short*)(X + 67108864);            // [256][128][512] bf16
    short* xW2  = (short*)(X + 100663296);           // [256][128][1536] bf16
    short* h_all = (short*)alloc(256ULL * 256 * 512 * 2);  // [t][s][512] bf16
    short* hb0 = (short*)alloc(256 * 512 * 2);
    short* hb1 = (short*)alloc(256 * 512 * 2);
    float* usumW = (float*)alloc(128 * 512 * 4);
    float* usumS = (float*)alloc(128 * 512 * 4);
    float* h2f   = (float*)alloc(128 * 512 * 4);

    if (off > ws_size) {
        fprintf(stderr, "kernel_launch: workspace too small: need %zu have %zu\n", off, ws_size);
        return;
    }

    auto cv = [&](const float* src, short* dst, int n) {
        int n4 = n / 4;
        f2bf_vec<<<(n4 + 255) / 256, 256, 0, stream>>>(src, dst, n4);
    };
    cv(embed, embed_bf, 50000 * 512);
    cv(Wi1, Wi1b, 1536 * 512);
    cv(Wh1, Wh1b, 1536 * 512);
    cv(Aw, Awb, 512 * 512);
    cv(As, Asb, 512 * 512);
    cv(Wi2, Wi2b, 1536 * 1024);
    cv(Wh2, Wh2b, 1536 * 512);

    // xW1 = gathered embeds @ Wi1^T + bi1, rows m = t*256 + s  (s<128: ask, else answer)
    gemm_bt<M_XW1><<<dim3(12, 512), 256, 0, stream>>>(
        embed_bf, nullptr, ask, answer, Wi1b, bi1, xW1, 65536, 1536, 512);

    // GRU1 over ask+ans combined (S=256)
    {
        int S = 256, t0 = 0, tend = 256, T = 256;
        void* args[] = { (void*)&xW1, (void*)&Wh1b, (void*)&bh1, (void*)&hb0, (void*)&hb1,
                         (void*)&h_all, (void*)&h2f, (void*)&S, (void*)&t0, (void*)&tend, (void*)&T };
        hipError_t e = hipLaunchCooperativeKernel(
            reinterpret_cast<void*>(&gru_scan<1, 1>), dim3(32, 8), dim3(64), args, 0, stream);
        if (e != hipSuccess) {
            short* cur = hb0; short* nxt = hb1;
            for (int t = 0; t < 256; t++) {
                gru_scan<1, 0><<<dim3(32, 8), 64, 0, stream>>>(
                    xW1, Wh1b, bh1, cur, nxt, h_all, nullptr, 256, t, t + 1, 256);
                short* tmp = cur; cur = nxt; nxt = tmp;
            }
        }
    }

    // word attention
    embed_sum_k<<<128, 256, 0, stream>>>(embed_bf, askkw, usumW);
    gemm_bt<M_UAW><<<dim3(4, 256), 256, 0, stream>>>(
        embed_bf, nullptr, askkw, nullptr, Awb, bw, uA, 32768, 512, 512);
    attn_combine<1><<<8192, 256, 0, stream>>>(uA, embed_bf, anskw, usumW, Ww, ctxW);

    // seq attention
    hall_sum_k<<<128, 256, 0, stream>>>(h_all, usumS);
    gemm_bt<M_UAS><<<dim3(4, 256), 256, 0, stream>>>(
        h_all, nullptr, nullptr, nullptr, Asb, bs, uA, 32768, 512, 512);
    attn_combine<0><<<8192, 256, 0, stream>>>(uA, h_all, nullptr, usumS, Ws, ctxS);

    // xW2 = [ctxW | ctxS] @ Wi2^T + bi2, rows m = t*128 + b
    gemm_bt<M_XW2><<<dim3(12, 256), 256, 0, stream>>>(
        ctxW, ctxS, nullptr, nullptr, Wi2b, bi2, xW2, 32768, 1536, 1024);

    // GRU2 (S=128), keep only final hidden state
    {
        int S = 128, t0 = 0, tend = 256, T = 256;
        void* args[] = { (void*)&xW2, (void*)&Wh2b, (void*)&bh2, (void*)&hb0, (void*)&hb1,
                         (void*)&h_all, (void*)&h2f, (void*)&S, (void*)&t0, (void*)&tend, (void*)&T };
        hipError_t e = hipLaunchCooperativeKernel(
            reinterpret_cast<void*>(&gru_scan<0, 1>), dim3(32, 4), dim3(64), args, 0, stream);
        if (e != hipSuccess) {
            short* cur = hb0; short* nxt = hb1;
            for (int t = 0; t < 256; t++) {
                gru_scan<0, 0><<<dim3(32, 4), 64, 0, stream>>>(
                    xW2, Wh2b, bh2, cur, nxt, nullptr, h2f, 128, t, t + 1, 256);
                short* tmp = cur; cur = nxt; nxt = tmp;
            }
        }
    }

    final_head_k<<<128, 64, 0, stream>>>(h2f, Wf, bfv, (float*)d_out);
}